// Round 5
// baseline (156.317 us; speedup 1.0000x reference)
//
#include <hip/hip_runtime.h>
#include <math.h>

#define H 1024
#define W 1024
#define OH 1016
#define OW 1016
#define BH 8           // output rows per band (1016 = 8*127 exact, no tail)
#define NBANDS 127
#define NCHUNK 4       // 4 column chunks of 256 output cols
#define EPS 1e-6f
#define INV25 (1.0f/25.0f)

// One WAVE (64 threads) per block; each wave owns a 256-col x 8-row output
// chunk and streams down it. No __syncthreads anywhere: the 5-row dx/dy ring
// is wave-private LDS, and DS ops execute in wave program order (reads of the
// dropped row are emitted before writes of the new row; sched_barrier pins it).
// Register state/thread: cs_x/cs_y[12] (input 5-row col sums, 12 cols),
// cp1..3[8] (product 5-row col sums, 8 cols).

__device__ __forceinline__ float4 ld4(const float* p){ return *reinterpret_cast<const float4*>(p); }
__device__ __forceinline__ void st4(float* p, float4 v){ *reinterpret_cast<float4*>(p) = v; }

__device__ __forceinline__ void load12(const float* p, float v[12]) {
    float4 a = ld4(p), b = ld4(p + 4), c = ld4(p + 8);
    v[0]=a.x; v[1]=a.y; v[2]=a.z;  v[3]=a.w;
    v[4]=b.x; v[5]=b.y; v[6]=b.z;  v[7]=b.w;
    v[8]=c.x; v[9]=c.y; v[10]=c.z; v[11]=c.w;
}

__global__ __launch_bounds__(64, 4)
void yiq_gngc_wave(const float* __restrict__ x, const float* __restrict__ y,
                   float* __restrict__ out, long long Nper)
{
    __shared__ __align__(16) float ring[5][2][264];   // 10560 B
    const int t  = (int)threadIdx.x;
    const int jc = (int)blockIdx.y * 256;
    const int maxj = (jc + 252 < OW - 4) ? (jc + 252) : (OW - 4);  // 1012 on last chunk
    int j0 = jc + 4 * t; if (j0 > maxj) j0 = maxj;    // clamped lanes duplicate (benign)
    const bool lastlane = (j0 == maxj);               // writes the 4-col ring halo too
    const int rel = j0 - jc;                          // 0..252
    const int i0 = (int)blockIdx.x * BH;
    const int b  = (int)blockIdx.z;
    const float* xb = x + (size_t)b * (H * W) + j0;
    const float* yb = y + (size_t)b * (H * W) + j0;

    float cs_x[12], cs_y[12];
    float cp1[8], cp2[8], cp3[8];
    #pragma unroll
    for (int k = 0; k < 12; ++k) { cs_x[k] = 0.f; cs_y[k] = 0.f; }
    #pragma unroll
    for (int k = 0; k < 8; ++k) { cp1[k] = 0.f; cp2[k] = 0.f; cp3[k] = 0.f; }

    // ---- initial input column sums over rows i0..i0+4 ----
    #pragma unroll
    for (int r = 0; r < 5; ++r) {
        float vx[12], vy[12];
        load12(xb + (size_t)(i0 + r) * W, vx);
        load12(yb + (size_t)(i0 + r) * W, vy);
        #pragma unroll
        for (int k = 0; k < 12; ++k) { cs_x[k] += vx[k]; cs_y[k] += vy[k]; }
    }

    // ---- zero ring slot 4 (the "row -1" subtracted at it=0) ----
    {
        float4 z = make_float4(0.f, 0.f, 0.f, 0.f);
        st4(&ring[4][0][rel], z); st4(&ring[4][1][rel], z);
        if (lastlane) { st4(&ring[4][0][rel + 4], z); st4(&ring[4][1][rel + 4], z); }
    }

    // ---- prime dx/dy rows i0..i0+3 into slots 0..3; accumulate cp ----
    #pragma unroll
    for (int pr = 0; pr < 4; ++pr) {
        float xc[12], yc[12];
        load12(xb + (size_t)(i0 + pr + 2) * W, xc);   // center row
        load12(yb + (size_t)(i0 + pr + 2) * W, yc);
        float dxn[8], dyn[8];
        #pragma unroll
        for (int k = 0; k < 8; ++k) {
            float sx = cs_x[k] + cs_x[k+1] + cs_x[k+2] + cs_x[k+3] + cs_x[k+4];
            float sy = cs_y[k] + cs_y[k+1] + cs_y[k+2] + cs_y[k+3] + cs_y[k+4];
            dxn[k] = xc[k + 2] - sx * INV25;
            dyn[k] = yc[k + 2] - sy * INV25;
            cp1[k] += dxn[k] * dyn[k];
            cp2[k] += dxn[k] * dxn[k];
            cp3[k] += dyn[k] * dyn[k];
        }
        st4(&ring[pr][0][rel], make_float4(dxn[0], dxn[1], dxn[2], dxn[3]));
        st4(&ring[pr][1][rel], make_float4(dyn[0], dyn[1], dyn[2], dyn[3]));
        if (lastlane) {
            st4(&ring[pr][0][rel + 4], make_float4(dxn[4], dxn[5], dxn[6], dxn[7]));
            st4(&ring[pr][1][rel + 4], make_float4(dyn[4], dyn[5], dyn[6], dyn[7]));
        }
        // slide cs: add row i0+pr+5, drop row i0+pr  (max row index i0+8 <= 1016)
        float nx[12], ox[12], ny[12], oy[12];
        load12(xb + (size_t)(i0 + pr + 5) * W, nx);
        load12(xb + (size_t)(i0 + pr) * W, ox);
        load12(yb + (size_t)(i0 + pr + 5) * W, ny);
        load12(yb + (size_t)(i0 + pr) * W, oy);
        #pragma unroll
        for (int k = 0; k < 12; ++k) { cs_x[k] += nx[k] - ox[k]; cs_y[k] += ny[k] - oy[k]; }
    }

    float* ob = out + (size_t)b * ((size_t)OH * OW) + j0;

    // ---- main loop: output rows i0..i0+7 (fully unrolled, static ring slots) ----
    #pragma unroll
    for (int it = 0; it < BH; ++it) {
        const int i = i0 + it;
        const int s = (it + 4) % 5;                  // slot of dropped row i-1 == new row i+4

        // center row for new dx/dy row i+4  (max row 1021)
        float xc[12], yc[12];
        load12(xb + (size_t)(i + 6) * W, xc);
        load12(yb + (size_t)(i + 6) * W, yc);

        // read old dx/dy (row i-1) BEFORE overwriting slot s
        float4 oxa = ld4(&ring[s][0][rel]);
        float4 oxb = ld4(&ring[s][0][rel + 4]);
        float4 oya = ld4(&ring[s][1][rel]);
        float4 oyb = ld4(&ring[s][1][rel + 4]);
        __builtin_amdgcn_sched_barrier(0);           // pin reads before ring writes (cross-lane RAW)

        // new dx/dy row i+4 (8 halo cols, in registers)
        float dxn[8], dyn[8];
        #pragma unroll
        for (int k = 0; k < 8; ++k) {
            float sx = cs_x[k] + cs_x[k+1] + cs_x[k+2] + cs_x[k+3] + cs_x[k+4];
            float sy = cs_y[k] + cs_y[k+1] + cs_y[k+2] + cs_y[k+3] + cs_y[k+4];
            dxn[k] = xc[k + 2] - sx * INV25;
            dyn[k] = yc[k + 2] - sy * INV25;
        }
        st4(&ring[s][0][rel], make_float4(dxn[0], dxn[1], dxn[2], dxn[3]));
        st4(&ring[s][1][rel], make_float4(dyn[0], dyn[1], dyn[2], dyn[3]));
        if (lastlane) {
            st4(&ring[s][0][rel + 4], make_float4(dxn[4], dxn[5], dxn[6], dxn[7]));
            st4(&ring[s][1][rel + 4], make_float4(dyn[4], dyn[5], dyn[6], dyn[7]));
        }

        // slide product column sums: + new row, - old row
        float odx[8] = {oxa.x, oxa.y, oxa.z, oxa.w, oxb.x, oxb.y, oxb.z, oxb.w};
        float ody[8] = {oya.x, oya.y, oya.z, oya.w, oyb.x, oyb.y, oyb.z, oyb.w};
        #pragma unroll
        for (int k = 0; k < 8; ++k) {
            cp1[k] += dxn[k] * dyn[k] - odx[k] * ody[k];
            cp2[k] += dxn[k] * dxn[k] - odx[k] * odx[k];
            cp3[k] += dyn[k] * dyn[k] - ody[k] * ody[k];
        }

        // finalize output row i, cols j0..j0+3
        float co[4], vv[4], cc[4];
        #pragma unroll
        for (int q = 0; q < 4; ++q) {
            float c_ = (cp1[q] + cp1[q+1] + cp1[q+2] + cp1[q+3] + cp1[q+4]) * INV25;
            float vx = (cp2[q] + cp2[q+1] + cp2[q+2] + cp2[q+3] + cp2[q+4]) * INV25;
            float vy = (cp3[q] + cp3[q+1] + cp3[q+2] + cp3[q+3] + cp3[q+4]) * INV25;
            float v  = sqrtf(vx * vy);
            bool lo  = v < EPS;
            float cv = lo ? 0.f : c_;
            float vs = lo ? EPS : v;
            float r_ = cv / vs;
            r_ = r_ < 0.f ? 0.f : (r_ > 1.f ? 1.f : r_);
            co[q] = r_; vv[q] = vs; cc[q] = cv;
        }
        float* o = ob + (size_t)i * OW;
        st4(o,            make_float4(co[0], co[1], co[2], co[3]));
        st4(o + Nper,     make_float4(vv[0], vv[1], vv[2], vv[3]));
        st4(o + 2 * Nper, make_float4(cc[0], cc[1], cc[2], cc[3]));

        // slide input column sums: add row i+9 (max 1023), drop row i+4
        if (it < BH - 1) {
            float nx[12], oxr[12], ny[12], oyr[12];
            load12(xb + (size_t)(i + 9) * W, nx);
            load12(xb + (size_t)(i + 4) * W, oxr);
            load12(yb + (size_t)(i + 9) * W, ny);
            load12(yb + (size_t)(i + 4) * W, oyr);
            #pragma unroll
            for (int k = 0; k < 12; ++k) { cs_x[k] += nx[k] - oxr[k]; cs_y[k] += ny[k] - oyr[k]; }
        }
    }
}

extern "C" void kernel_launch(void* const* d_in, const int* in_sizes, int n_in,
                              void* d_out, int out_size, void* d_ws, size_t ws_size,
                              hipStream_t stream) {
    const float* x = (const float*)d_in[0];
    const float* y = (const float*)d_in[1];
    // mask (d_in[2]) unused by the reference's channels==1 path
    float* out = (float*)d_out;
    const int B = in_sizes[0] / (H * W);
    const long long Nper = (long long)out_size / 3;   // elements per output array
    dim3 grid(NBANDS, NCHUNK, B);
    yiq_gngc_wave<<<grid, dim3(64), 0, stream>>>(x, y, out, Nper);
}

// Round 6
// 63.106 us; speedup vs baseline: 2.4771x; 2.4771x over previous
//
#include <hip/hip_runtime.h>
#include <math.h>

#define H 1024
#define W 1024
#define OH 1016
#define OW 1016
#define BH 8           // output rows per band (1016 = 8*127 exact, no tail)
#define NBANDS 127
#define NCHUNK 4       // 4 column chunks of 256 output cols
#define EPS 1e-6f
#define INV25 (1.0f/25.0f)

// One WAVE (64 threads) per block; each wave owns a 256-col x 8-row output
// chunk and streams down it. No __syncthreads anywhere: the 5-row dx/dy ring
// is wave-private LDS, and DS ops execute in wave program order (reads of the
// dropped row are emitted before writes of the new row; sched_barrier pins it).
// Register state/thread: cs_x/cs_y[12] (input 5-row col sums, 12 cols),
// cp1..3[8] (product 5-row col sums, 8 cols).
// launch_bounds(64,2): VGPR cap 256. (64,4) in R5 forced VGPR=64 -> scratch
// spill (FETCH/WRITE ballooned to 287/281 MB). Do not tighten this.

__device__ __forceinline__ float4 ld4(const float* p){ return *reinterpret_cast<const float4*>(p); }
__device__ __forceinline__ void st4(float* p, float4 v){ *reinterpret_cast<float4*>(p) = v; }

__device__ __forceinline__ void load12(const float* p, float v[12]) {
    float4 a = ld4(p), b = ld4(p + 4), c = ld4(p + 8);
    v[0]=a.x; v[1]=a.y; v[2]=a.z;  v[3]=a.w;
    v[4]=b.x; v[5]=b.y; v[6]=b.z;  v[7]=b.w;
    v[8]=c.x; v[9]=c.y; v[10]=c.z; v[11]=c.w;
}

__global__ __launch_bounds__(64, 2)
void yiq_gngc_wave(const float* __restrict__ x, const float* __restrict__ y,
                   float* __restrict__ out, long long Nper)
{
    __shared__ __align__(16) float ring[5][2][264];   // 10560 B
    const int t  = (int)threadIdx.x;
    const int jc = (int)blockIdx.y * 256;
    const int maxj = (jc + 252 < OW - 4) ? (jc + 252) : (OW - 4);  // 1012 on last chunk
    int j0 = jc + 4 * t; if (j0 > maxj) j0 = maxj;    // clamped lanes duplicate (benign)
    const bool lastlane = (j0 == maxj);               // writes the 4-col ring halo too
    const int rel = j0 - jc;                          // 0..252
    const int i0 = (int)blockIdx.x * BH;
    const int b  = (int)blockIdx.z;
    const float* xb = x + (size_t)b * (H * W) + j0;
    const float* yb = y + (size_t)b * (H * W) + j0;

    float cs_x[12], cs_y[12];
    float cp1[8], cp2[8], cp3[8];
    #pragma unroll
    for (int k = 0; k < 12; ++k) { cs_x[k] = 0.f; cs_y[k] = 0.f; }
    #pragma unroll
    for (int k = 0; k < 8; ++k) { cp1[k] = 0.f; cp2[k] = 0.f; cp3[k] = 0.f; }

    // ---- initial input column sums over rows i0..i0+4 (x then y: fewer live temps) ----
    #pragma unroll
    for (int r = 0; r < 5; ++r) {
        float vx[12];
        load12(xb + (size_t)(i0 + r) * W, vx);
        #pragma unroll
        for (int k = 0; k < 12; ++k) cs_x[k] += vx[k];
    }
    #pragma unroll
    for (int r = 0; r < 5; ++r) {
        float vy[12];
        load12(yb + (size_t)(i0 + r) * W, vy);
        #pragma unroll
        for (int k = 0; k < 12; ++k) cs_y[k] += vy[k];
    }

    // ---- zero ring slot 4 (the "row -1" subtracted at it=0) ----
    {
        float4 z = make_float4(0.f, 0.f, 0.f, 0.f);
        st4(&ring[4][0][rel], z); st4(&ring[4][1][rel], z);
        if (lastlane) { st4(&ring[4][0][rel + 4], z); st4(&ring[4][1][rel + 4], z); }
    }

    // ---- prime dx/dy rows i0..i0+3 into slots 0..3; accumulate cp ----
    #pragma unroll
    for (int pr = 0; pr < 4; ++pr) {
        float xc[12], yc[12];
        load12(xb + (size_t)(i0 + pr + 2) * W, xc);   // center row
        load12(yb + (size_t)(i0 + pr + 2) * W, yc);
        float dxn[8], dyn[8];
        #pragma unroll
        for (int k = 0; k < 8; ++k) {
            float sx = cs_x[k] + cs_x[k+1] + cs_x[k+2] + cs_x[k+3] + cs_x[k+4];
            float sy = cs_y[k] + cs_y[k+1] + cs_y[k+2] + cs_y[k+3] + cs_y[k+4];
            dxn[k] = xc[k + 2] - sx * INV25;
            dyn[k] = yc[k + 2] - sy * INV25;
            cp1[k] += dxn[k] * dyn[k];
            cp2[k] += dxn[k] * dxn[k];
            cp3[k] += dyn[k] * dyn[k];
        }
        st4(&ring[pr][0][rel], make_float4(dxn[0], dxn[1], dxn[2], dxn[3]));
        st4(&ring[pr][1][rel], make_float4(dyn[0], dyn[1], dyn[2], dyn[3]));
        if (lastlane) {
            st4(&ring[pr][0][rel + 4], make_float4(dxn[4], dxn[5], dxn[6], dxn[7]));
            st4(&ring[pr][1][rel + 4], make_float4(dyn[4], dyn[5], dyn[6], dyn[7]));
        }
        // slide cs: add row i0+pr+5, drop row i0+pr (x-pair then y-pair)
        {
            float nx[12], ox[12];
            load12(xb + (size_t)(i0 + pr + 5) * W, nx);
            load12(xb + (size_t)(i0 + pr) * W, ox);
            #pragma unroll
            for (int k = 0; k < 12; ++k) cs_x[k] += nx[k] - ox[k];
        }
        {
            float ny[12], oy[12];
            load12(yb + (size_t)(i0 + pr + 5) * W, ny);
            load12(yb + (size_t)(i0 + pr) * W, oy);
            #pragma unroll
            for (int k = 0; k < 12; ++k) cs_y[k] += ny[k] - oy[k];
        }
    }

    float* ob = out + (size_t)b * ((size_t)OH * OW) + j0;

    // ---- main loop: output rows i0..i0+7 (fully unrolled, static ring slots) ----
    #pragma unroll
    for (int it = 0; it < BH; ++it) {
        const int i = i0 + it;
        const int s = (it + 4) % 5;                  // slot of dropped row i-1 == new row i+4

        // center row for new dx/dy row i+4  (max row 1021)
        float xc[12], yc[12];
        load12(xb + (size_t)(i + 6) * W, xc);
        load12(yb + (size_t)(i + 6) * W, yc);

        // read old dx/dy (row i-1) BEFORE overwriting slot s
        float4 oxa = ld4(&ring[s][0][rel]);
        float4 oxb = ld4(&ring[s][0][rel + 4]);
        float4 oya = ld4(&ring[s][1][rel]);
        float4 oyb = ld4(&ring[s][1][rel + 4]);
        __builtin_amdgcn_sched_barrier(0);           // pin reads before ring writes (cross-lane RAW)

        // new dx/dy row i+4 (8 halo cols, in registers)
        float dxn[8], dyn[8];
        #pragma unroll
        for (int k = 0; k < 8; ++k) {
            float sx = cs_x[k] + cs_x[k+1] + cs_x[k+2] + cs_x[k+3] + cs_x[k+4];
            float sy = cs_y[k] + cs_y[k+1] + cs_y[k+2] + cs_y[k+3] + cs_y[k+4];
            dxn[k] = xc[k + 2] - sx * INV25;
            dyn[k] = yc[k + 2] - sy * INV25;
        }
        st4(&ring[s][0][rel], make_float4(dxn[0], dxn[1], dxn[2], dxn[3]));
        st4(&ring[s][1][rel], make_float4(dyn[0], dyn[1], dyn[2], dyn[3]));
        if (lastlane) {
            st4(&ring[s][0][rel + 4], make_float4(dxn[4], dxn[5], dxn[6], dxn[7]));
            st4(&ring[s][1][rel + 4], make_float4(dyn[4], dyn[5], dyn[6], dyn[7]));
        }

        // slide product column sums: + new row, - old row
        float odx[8] = {oxa.x, oxa.y, oxa.z, oxa.w, oxb.x, oxb.y, oxb.z, oxb.w};
        float ody[8] = {oya.x, oya.y, oya.z, oya.w, oyb.x, oyb.y, oyb.z, oyb.w};
        #pragma unroll
        for (int k = 0; k < 8; ++k) {
            cp1[k] += dxn[k] * dyn[k] - odx[k] * ody[k];
            cp2[k] += dxn[k] * dxn[k] - odx[k] * odx[k];
            cp3[k] += dyn[k] * dyn[k] - ody[k] * ody[k];
        }

        // finalize output row i, cols j0..j0+3
        float co[4], vv[4], cc[4];
        #pragma unroll
        for (int q = 0; q < 4; ++q) {
            float c_ = (cp1[q] + cp1[q+1] + cp1[q+2] + cp1[q+3] + cp1[q+4]) * INV25;
            float vx = (cp2[q] + cp2[q+1] + cp2[q+2] + cp2[q+3] + cp2[q+4]) * INV25;
            float vy = (cp3[q] + cp3[q+1] + cp3[q+2] + cp3[q+3] + cp3[q+4]) * INV25;
            float v  = sqrtf(vx * vy);
            bool lo  = v < EPS;
            float cv = lo ? 0.f : c_;
            float vs = lo ? EPS : v;
            float r_ = cv / vs;
            r_ = r_ < 0.f ? 0.f : (r_ > 1.f ? 1.f : r_);
            co[q] = r_; vv[q] = vs; cc[q] = cv;
        }
        float* o = ob + (size_t)i * OW;
        st4(o,            make_float4(co[0], co[1], co[2], co[3]));
        st4(o + Nper,     make_float4(vv[0], vv[1], vv[2], vv[3]));
        st4(o + 2 * Nper, make_float4(cc[0], cc[1], cc[2], cc[3]));

        // slide input column sums: add row i+9 (max 1023), drop row i+4
        if (it < BH - 1) {
            {
                float nx[12], oxr[12];
                load12(xb + (size_t)(i + 9) * W, nx);
                load12(xb + (size_t)(i + 4) * W, oxr);
                #pragma unroll
                for (int k = 0; k < 12; ++k) cs_x[k] += nx[k] - oxr[k];
            }
            {
                float ny[12], oyr[12];
                load12(yb + (size_t)(i + 9) * W, ny);
                load12(yb + (size_t)(i + 4) * W, oyr);
                #pragma unroll
                for (int k = 0; k < 12; ++k) cs_y[k] += ny[k] - oyr[k];
            }
        }
    }
}

extern "C" void kernel_launch(void* const* d_in, const int* in_sizes, int n_in,
                              void* d_out, int out_size, void* d_ws, size_t ws_size,
                              hipStream_t stream) {
    const float* x = (const float*)d_in[0];
    const float* y = (const float*)d_in[1];
    // mask (d_in[2]) unused by the reference's channels==1 path
    float* out = (float*)d_out;
    const int B = in_sizes[0] / (H * W);
    const long long Nper = (long long)out_size / 3;   // elements per output array
    dim3 grid(NBANDS, NCHUNK, B);
    yiq_gngc_wave<<<grid, dim3(64), 0, stream>>>(x, y, out, Nper);
}

// Round 7
// 60.813 us; speedup vs baseline: 2.5705x; 1.0377x over previous
//
#include <hip/hip_runtime.h>
#include <math.h>

#define H 1024
#define W 1024
#define OH 1016
#define OW 1016
#define BH 8           // output rows per band (1016 = 8*127 exact, no tail)
#define NBANDS 127
#define NCHUNK 4       // 4 column chunks of 256 output cols
#define EPS 1e-6f
#define INV25 (1.0f/25.0f)

// One WAVE (64 threads) per block; each wave owns a 256-col x 8-row output
// chunk and streams down it. NO barriers and NO sched fences: every LDS read
// in the dx/dy ring is same-address with a later LDS write by the SAME lane
// (compiler must preserve order; DS ops execute in wave program order), and
// the cross-lane halo is moved through registers via __shfl_down instead of
// LDS. The seam lane reads its own halo slot (again same-address ordered).
// R5 lesson: launch_bounds(64,4) forced VGPR=64 -> scratch spill. Keep (64,2).
// R6 lesson: per-iteration sched_barrier(0) blocked software pipelining.

__device__ __forceinline__ float4 ld4(const float* p){ return *reinterpret_cast<const float4*>(p); }
__device__ __forceinline__ void st4(float* p, float4 v){ *reinterpret_cast<float4*>(p) = v; }

__device__ __forceinline__ void load12(const float* p, float v[12]) {
    float4 a = ld4(p), b = ld4(p + 4), c = ld4(p + 8);
    v[0]=a.x; v[1]=a.y; v[2]=a.z;  v[3]=a.w;
    v[4]=b.x; v[5]=b.y; v[6]=b.z;  v[7]=b.w;
    v[8]=c.x; v[9]=c.y; v[10]=c.z; v[11]=c.w;
}

__global__ __launch_bounds__(64, 2)
void yiq_gngc_wave(const float* __restrict__ x, const float* __restrict__ y,
                   float* __restrict__ out, long long Nper)
{
    __shared__ __align__(16) float ring[5][2][264];   // 10560 B
    const int t  = (int)threadIdx.x;
    const int jc = (int)blockIdx.y * 256;
    const int maxj = (jc + 252 < OW - 4) ? (jc + 252) : (OW - 4);  // 1012 on last chunk
    int j0 = jc + 4 * t; if (j0 > maxj) j0 = maxj;    // clamped lanes duplicate (benign)
    const bool lastlane = (j0 == maxj);               // owns the 4-col ring halo
    const int rel = j0 - jc;                          // 0..252
    const int i0 = (int)blockIdx.x * BH;
    const int b  = (int)blockIdx.z;
    const float* xb = x + (size_t)b * (H * W) + j0;
    const float* yb = y + (size_t)b * (H * W) + j0;

    float cs_x[12], cs_y[12];
    float cp1[8], cp2[8], cp3[8];
    #pragma unroll
    for (int k = 0; k < 12; ++k) { cs_x[k] = 0.f; cs_y[k] = 0.f; }
    #pragma unroll
    for (int k = 0; k < 8; ++k) { cp1[k] = 0.f; cp2[k] = 0.f; cp3[k] = 0.f; }

    // ---- initial input column sums over rows i0..i0+4 (x then y) ----
    #pragma unroll
    for (int r = 0; r < 5; ++r) {
        float vx[12];
        load12(xb + (size_t)(i0 + r) * W, vx);
        #pragma unroll
        for (int k = 0; k < 12; ++k) cs_x[k] += vx[k];
    }
    #pragma unroll
    for (int r = 0; r < 5; ++r) {
        float vy[12];
        load12(yb + (size_t)(i0 + r) * W, vy);
        #pragma unroll
        for (int k = 0; k < 12; ++k) cs_y[k] += vy[k];
    }

    // ---- zero ring slot 4 (the "row -1" subtracted at it=0) ----
    {
        float4 z = make_float4(0.f, 0.f, 0.f, 0.f);
        st4(&ring[4][0][rel], z); st4(&ring[4][1][rel], z);
        if (lastlane) { st4(&ring[4][0][rel + 4], z); st4(&ring[4][1][rel + 4], z); }
    }

    // ---- prime dx/dy rows i0..i0+3 into slots 0..3; accumulate cp ----
    #pragma unroll
    for (int pr = 0; pr < 4; ++pr) {
        float xc[12], yc[12];
        load12(xb + (size_t)(i0 + pr + 2) * W, xc);   // center row
        load12(yb + (size_t)(i0 + pr + 2) * W, yc);
        float dxn[8], dyn[8];
        #pragma unroll
        for (int k = 0; k < 8; ++k) {
            float sx = cs_x[k] + cs_x[k+1] + cs_x[k+2] + cs_x[k+3] + cs_x[k+4];
            float sy = cs_y[k] + cs_y[k+1] + cs_y[k+2] + cs_y[k+3] + cs_y[k+4];
            dxn[k] = xc[k + 2] - sx * INV25;
            dyn[k] = yc[k + 2] - sy * INV25;
            cp1[k] += dxn[k] * dyn[k];
            cp2[k] += dxn[k] * dxn[k];
            cp3[k] += dyn[k] * dyn[k];
        }
        st4(&ring[pr][0][rel], make_float4(dxn[0], dxn[1], dxn[2], dxn[3]));
        st4(&ring[pr][1][rel], make_float4(dyn[0], dyn[1], dyn[2], dyn[3]));
        if (lastlane) {
            st4(&ring[pr][0][rel + 4], make_float4(dxn[4], dxn[5], dxn[6], dxn[7]));
            st4(&ring[pr][1][rel + 4], make_float4(dyn[4], dyn[5], dyn[6], dyn[7]));
        }
        // slide cs: add row i0+pr+5, drop row i0+pr (x-pair then y-pair)
        {
            float nx[12], ox[12];
            load12(xb + (size_t)(i0 + pr + 5) * W, nx);
            load12(xb + (size_t)(i0 + pr) * W, ox);
            #pragma unroll
            for (int k = 0; k < 12; ++k) cs_x[k] += nx[k] - ox[k];
        }
        {
            float ny[12], oy[12];
            load12(yb + (size_t)(i0 + pr + 5) * W, ny);
            load12(yb + (size_t)(i0 + pr) * W, oy);
            #pragma unroll
            for (int k = 0; k < 12; ++k) cs_y[k] += ny[k] - oy[k];
        }
    }

    float* ob = out + (size_t)b * ((size_t)OH * OW) + j0;

    // ---- main loop: output rows i0..i0+7 (fully unrolled, static ring slots) ----
    #pragma unroll
    for (int it = 0; it < BH; ++it) {
        const int i = i0 + it;
        const int s = (it + 4) % 5;                  // slot of dropped row i-1 == new row i+4

        // center row for new dx/dy row i+4  (max row 1021)
        float xc[12], yc[12];
        load12(xb + (size_t)(i + 6) * W, xc);
        load12(yb + (size_t)(i + 6) * W, yc);

        // --- old dx/dy (row i-1): own 4 from LDS (same-address as the write
        //     below -> compiler-ordered), halo 4 via shfl from lane t+1 ---
        float4 oox = ld4(&ring[s][0][rel]);
        float4 ooy = ld4(&ring[s][1][rel]);
        float hx0 = __shfl_down(oox.x, 1), hx1 = __shfl_down(oox.y, 1);
        float hx2 = __shfl_down(oox.z, 1), hx3 = __shfl_down(oox.w, 1);
        float hy0 = __shfl_down(ooy.x, 1), hy1 = __shfl_down(ooy.y, 1);
        float hy2 = __shfl_down(ooy.z, 1), hy3 = __shfl_down(ooy.w, 1);
        if (lastlane) {   // seam lane: halo from its own rel+4 slot (same-address ordered)
            float4 dhx = ld4(&ring[s][0][rel + 4]);
            float4 dhy = ld4(&ring[s][1][rel + 4]);
            hx0 = dhx.x; hx1 = dhx.y; hx2 = dhx.z; hx3 = dhx.w;
            hy0 = dhy.x; hy1 = dhy.y; hy2 = dhy.z; hy3 = dhy.w;
        }

        // new dx/dy row i+4 (8 halo cols, in registers)
        float dxn[8], dyn[8];
        #pragma unroll
        for (int k = 0; k < 8; ++k) {
            float sx = cs_x[k] + cs_x[k+1] + cs_x[k+2] + cs_x[k+3] + cs_x[k+4];
            float sy = cs_y[k] + cs_y[k+1] + cs_y[k+2] + cs_y[k+3] + cs_y[k+4];
            dxn[k] = xc[k + 2] - sx * INV25;
            dyn[k] = yc[k + 2] - sy * INV25;
        }
        st4(&ring[s][0][rel], make_float4(dxn[0], dxn[1], dxn[2], dxn[3]));
        st4(&ring[s][1][rel], make_float4(dyn[0], dyn[1], dyn[2], dyn[3]));
        if (lastlane) {
            st4(&ring[s][0][rel + 4], make_float4(dxn[4], dxn[5], dxn[6], dxn[7]));
            st4(&ring[s][1][rel + 4], make_float4(dyn[4], dyn[5], dyn[6], dyn[7]));
        }

        // slide product column sums: + new row, - old row
        float odx[8] = {oox.x, oox.y, oox.z, oox.w, hx0, hx1, hx2, hx3};
        float ody[8] = {ooy.x, ooy.y, ooy.z, ooy.w, hy0, hy1, hy2, hy3};
        #pragma unroll
        for (int k = 0; k < 8; ++k) {
            cp1[k] += dxn[k] * dyn[k] - odx[k] * ody[k];
            cp2[k] += dxn[k] * dxn[k] - odx[k] * odx[k];
            cp3[k] += dyn[k] * dyn[k] - ody[k] * ody[k];
        }

        // finalize output row i, cols j0..j0+3
        float co[4], vv[4], cc[4];
        #pragma unroll
        for (int q = 0; q < 4; ++q) {
            float c_ = (cp1[q] + cp1[q+1] + cp1[q+2] + cp1[q+3] + cp1[q+4]) * INV25;
            float vx = (cp2[q] + cp2[q+1] + cp2[q+2] + cp2[q+3] + cp2[q+4]) * INV25;
            float vy = (cp3[q] + cp3[q+1] + cp3[q+2] + cp3[q+3] + cp3[q+4]) * INV25;
            float v  = sqrtf(vx * vy);
            bool lo  = v < EPS;
            float cv = lo ? 0.f : c_;
            float vs = lo ? EPS : v;
            float r_ = cv / vs;
            r_ = r_ < 0.f ? 0.f : (r_ > 1.f ? 1.f : r_);
            co[q] = r_; vv[q] = vs; cc[q] = cv;
        }
        float* o = ob + (size_t)i * OW;
        st4(o,            make_float4(co[0], co[1], co[2], co[3]));
        st4(o + Nper,     make_float4(vv[0], vv[1], vv[2], vv[3]));
        st4(o + 2 * Nper, make_float4(cc[0], cc[1], cc[2], cc[3]));

        // slide input column sums: add row i+9 (max 1023), drop row i+4
        if (it < BH - 1) {
            {
                float nx[12], oxr[12];
                load12(xb + (size_t)(i + 9) * W, nx);
                load12(xb + (size_t)(i + 4) * W, oxr);
                #pragma unroll
                for (int k = 0; k < 12; ++k) cs_x[k] += nx[k] - oxr[k];
            }
            {
                float ny[12], oyr[12];
                load12(yb + (size_t)(i + 9) * W, ny);
                load12(yb + (size_t)(i + 4) * W, oyr);
                #pragma unroll
                for (int k = 0; k < 12; ++k) cs_y[k] += ny[k] - oyr[k];
            }
        }
    }
}

extern "C" void kernel_launch(void* const* d_in, const int* in_sizes, int n_in,
                              void* d_out, int out_size, void* d_ws, size_t ws_size,
                              hipStream_t stream) {
    const float* x = (const float*)d_in[0];
    const float* y = (const float*)d_in[1];
    // mask (d_in[2]) unused by the reference's channels==1 path
    float* out = (float*)d_out;
    const int B = in_sizes[0] / (H * W);
    const long long Nper = (long long)out_size / 3;   // elements per output array
    dim3 grid(NBANDS, NCHUNK, B);
    yiq_gngc_wave<<<grid, dim3(64), 0, stream>>>(x, y, out, Nper);
}

// Round 8
// 58.932 us; speedup vs baseline: 2.6525x; 1.0319x over previous
//
#include <hip/hip_runtime.h>
#include <math.h>

#define H 1024
#define W 1024
#define OH 1016
#define OW 1016
#define BH 8           // output rows per band (1016 = 8*127 exact, no tail)
#define NBANDS 127
#define NCHUNK 4       // 4 column chunks of 256 output cols
#define NIMG 8
#define NWG (NBANDS*NCHUNK*NIMG)   // 4064, divisible by 8 (bijective XCD swizzle)
#define EPS 1e-6f
#define INV25 (1.0f/25.0f)

// One WAVE (64 threads) per block; each wave owns a 256-col x 8-row output
// chunk and streams down it. No barriers / no sched fences (R7 structure):
// dx/dy ring reads are same-address-per-lane (compiler-ordered vs the later
// write), halo moves through __shfl_down registers.
// R5 lesson: launch_bounds(64,4) forced VGPR=64 -> scratch spill. Keep (64,2).
// R6 lesson: per-iteration sched_barrier(0) blocked software pipelining.
// R8: XCD-aware swizzle (T1). Flat grid; nid=(wg%8)*(NWG/8)+wg/8 puts each
// image's 508 blocks on ONE XCD with adjacent bands adjacent in dispatch ->
// the 9 halo rows shared by neighboring bands hit that XCD's L2 instead of
// being re-fetched from HBM (R7 FETCH=123MB vs 64MB logical).

__device__ __forceinline__ float4 ld4(const float* p){ return *reinterpret_cast<const float4*>(p); }
__device__ __forceinline__ void st4(float* p, float4 v){ *reinterpret_cast<float4*>(p) = v; }

__device__ __forceinline__ void load12(const float* p, float v[12]) {
    float4 a = ld4(p), b = ld4(p + 4), c = ld4(p + 8);
    v[0]=a.x; v[1]=a.y; v[2]=a.z;  v[3]=a.w;
    v[4]=b.x; v[5]=b.y; v[6]=b.z;  v[7]=b.w;
    v[8]=c.x; v[9]=c.y; v[10]=c.z; v[11]=c.w;
}

__global__ __launch_bounds__(64, 2)
void yiq_gngc_wave(const float* __restrict__ x, const float* __restrict__ y,
                   float* __restrict__ out, long long Nper)
{
    __shared__ __align__(16) float ring[5][2][264];   // 10560 B
    const int t  = (int)threadIdx.x;

    // ---- XCD-aware bijective swizzle (NWG % 8 == 0) ----
    const int wg  = (int)blockIdx.x;
    const int nid = (wg & 7) * (NWG / 8) + (wg >> 3);
    const int band  = nid % NBANDS;
    const int rest  = nid / NBANDS;        // 0..31
    const int chunk = rest & 3;
    const int b     = rest >> 2;           // image 0..7  (== XCD id)

    const int jc = chunk * 256;
    const int maxj = (jc + 252 < OW - 4) ? (jc + 252) : (OW - 4);  // 1012 on last chunk
    int j0 = jc + 4 * t; if (j0 > maxj) j0 = maxj;    // clamped lanes duplicate (benign)
    const bool lastlane = (j0 == maxj);               // owns the 4-col ring halo
    const int rel = j0 - jc;                          // 0..252
    const int i0 = band * BH;
    const float* xb = x + (size_t)b * (H * W) + j0;
    const float* yb = y + (size_t)b * (H * W) + j0;

    float cs_x[12], cs_y[12];
    float cp1[8], cp2[8], cp3[8];
    #pragma unroll
    for (int k = 0; k < 12; ++k) { cs_x[k] = 0.f; cs_y[k] = 0.f; }
    #pragma unroll
    for (int k = 0; k < 8; ++k) { cp1[k] = 0.f; cp2[k] = 0.f; cp3[k] = 0.f; }

    // ---- initial input column sums over rows i0..i0+4 (x then y) ----
    #pragma unroll
    for (int r = 0; r < 5; ++r) {
        float vx[12];
        load12(xb + (size_t)(i0 + r) * W, vx);
        #pragma unroll
        for (int k = 0; k < 12; ++k) cs_x[k] += vx[k];
    }
    #pragma unroll
    for (int r = 0; r < 5; ++r) {
        float vy[12];
        load12(yb + (size_t)(i0 + r) * W, vy);
        #pragma unroll
        for (int k = 0; k < 12; ++k) cs_y[k] += vy[k];
    }

    // ---- zero ring slot 4 (the "row -1" subtracted at it=0) ----
    {
        float4 z = make_float4(0.f, 0.f, 0.f, 0.f);
        st4(&ring[4][0][rel], z); st4(&ring[4][1][rel], z);
        if (lastlane) { st4(&ring[4][0][rel + 4], z); st4(&ring[4][1][rel + 4], z); }
    }

    // ---- prime dx/dy rows i0..i0+3 into slots 0..3; accumulate cp ----
    #pragma unroll
    for (int pr = 0; pr < 4; ++pr) {
        float xc[12], yc[12];
        load12(xb + (size_t)(i0 + pr + 2) * W, xc);   // center row
        load12(yb + (size_t)(i0 + pr + 2) * W, yc);
        float dxn[8], dyn[8];
        #pragma unroll
        for (int k = 0; k < 8; ++k) {
            float sx = cs_x[k] + cs_x[k+1] + cs_x[k+2] + cs_x[k+3] + cs_x[k+4];
            float sy = cs_y[k] + cs_y[k+1] + cs_y[k+2] + cs_y[k+3] + cs_y[k+4];
            dxn[k] = xc[k + 2] - sx * INV25;
            dyn[k] = yc[k + 2] - sy * INV25;
            cp1[k] += dxn[k] * dyn[k];
            cp2[k] += dxn[k] * dxn[k];
            cp3[k] += dyn[k] * dyn[k];
        }
        st4(&ring[pr][0][rel], make_float4(dxn[0], dxn[1], dxn[2], dxn[3]));
        st4(&ring[pr][1][rel], make_float4(dyn[0], dyn[1], dyn[2], dyn[3]));
        if (lastlane) {
            st4(&ring[pr][0][rel + 4], make_float4(dxn[4], dxn[5], dxn[6], dxn[7]));
            st4(&ring[pr][1][rel + 4], make_float4(dyn[4], dyn[5], dyn[6], dyn[7]));
        }
        // slide cs: add row i0+pr+5, drop row i0+pr (x-pair then y-pair)
        {
            float nx[12], ox[12];
            load12(xb + (size_t)(i0 + pr + 5) * W, nx);
            load12(xb + (size_t)(i0 + pr) * W, ox);
            #pragma unroll
            for (int k = 0; k < 12; ++k) cs_x[k] += nx[k] - ox[k];
        }
        {
            float ny[12], oy[12];
            load12(yb + (size_t)(i0 + pr + 5) * W, ny);
            load12(yb + (size_t)(i0 + pr) * W, oy);
            #pragma unroll
            for (int k = 0; k < 12; ++k) cs_y[k] += ny[k] - oy[k];
        }
    }

    float* ob = out + (size_t)b * ((size_t)OH * OW) + j0;

    // ---- main loop: output rows i0..i0+7 (fully unrolled, static ring slots) ----
    #pragma unroll
    for (int it = 0; it < BH; ++it) {
        const int i = i0 + it;
        const int s = (it + 4) % 5;                  // slot of dropped row i-1 == new row i+4

        // center row for new dx/dy row i+4  (max row 1021)
        float xc[12], yc[12];
        load12(xb + (size_t)(i + 6) * W, xc);
        load12(yb + (size_t)(i + 6) * W, yc);

        // --- old dx/dy (row i-1): own 4 from LDS (same-address as the write
        //     below -> compiler-ordered), halo 4 via shfl from lane t+1 ---
        float4 oox = ld4(&ring[s][0][rel]);
        float4 ooy = ld4(&ring[s][1][rel]);
        float hx0 = __shfl_down(oox.x, 1), hx1 = __shfl_down(oox.y, 1);
        float hx2 = __shfl_down(oox.z, 1), hx3 = __shfl_down(oox.w, 1);
        float hy0 = __shfl_down(ooy.x, 1), hy1 = __shfl_down(ooy.y, 1);
        float hy2 = __shfl_down(ooy.z, 1), hy3 = __shfl_down(ooy.w, 1);
        if (lastlane) {   // seam lane: halo from its own rel+4 slot (same-address ordered)
            float4 dhx = ld4(&ring[s][0][rel + 4]);
            float4 dhy = ld4(&ring[s][1][rel + 4]);
            hx0 = dhx.x; hx1 = dhx.y; hx2 = dhx.z; hx3 = dhx.w;
            hy0 = dhy.x; hy1 = dhy.y; hy2 = dhy.z; hy3 = dhy.w;
        }

        // new dx/dy row i+4 (8 halo cols, in registers)
        float dxn[8], dyn[8];
        #pragma unroll
        for (int k = 0; k < 8; ++k) {
            float sx = cs_x[k] + cs_x[k+1] + cs_x[k+2] + cs_x[k+3] + cs_x[k+4];
            float sy = cs_y[k] + cs_y[k+1] + cs_y[k+2] + cs_y[k+3] + cs_y[k+4];
            dxn[k] = xc[k + 2] - sx * INV25;
            dyn[k] = yc[k + 2] - sy * INV25;
        }
        st4(&ring[s][0][rel], make_float4(dxn[0], dxn[1], dxn[2], dxn[3]));
        st4(&ring[s][1][rel], make_float4(dyn[0], dyn[1], dyn[2], dyn[3]));
        if (lastlane) {
            st4(&ring[s][0][rel + 4], make_float4(dxn[4], dxn[5], dxn[6], dxn[7]));
            st4(&ring[s][1][rel + 4], make_float4(dyn[4], dyn[5], dyn[6], dyn[7]));
        }

        // slide product column sums: + new row, - old row
        float odx[8] = {oox.x, oox.y, oox.z, oox.w, hx0, hx1, hx2, hx3};
        float ody[8] = {ooy.x, ooy.y, ooy.z, ooy.w, hy0, hy1, hy2, hy3};
        #pragma unroll
        for (int k = 0; k < 8; ++k) {
            cp1[k] += dxn[k] * dyn[k] - odx[k] * ody[k];
            cp2[k] += dxn[k] * dxn[k] - odx[k] * odx[k];
            cp3[k] += dyn[k] * dyn[k] - ody[k] * ody[k];
        }

        // finalize output row i, cols j0..j0+3
        float co[4], vv[4], cc[4];
        #pragma unroll
        for (int q = 0; q < 4; ++q) {
            float c_ = (cp1[q] + cp1[q+1] + cp1[q+2] + cp1[q+3] + cp1[q+4]) * INV25;
            float vx = (cp2[q] + cp2[q+1] + cp2[q+2] + cp2[q+3] + cp2[q+4]) * INV25;
            float vy = (cp3[q] + cp3[q+1] + cp3[q+2] + cp3[q+3] + cp3[q+4]) * INV25;
            float v  = sqrtf(vx * vy);
            bool lo  = v < EPS;
            float cv = lo ? 0.f : c_;
            float vs = lo ? EPS : v;
            float r_ = cv / vs;
            r_ = r_ < 0.f ? 0.f : (r_ > 1.f ? 1.f : r_);
            co[q] = r_; vv[q] = vs; cc[q] = cv;
        }
        float* o = ob + (size_t)i * OW;
        st4(o,            make_float4(co[0], co[1], co[2], co[3]));
        st4(o + Nper,     make_float4(vv[0], vv[1], vv[2], vv[3]));
        st4(o + 2 * Nper, make_float4(cc[0], cc[1], cc[2], cc[3]));

        // slide input column sums: add row i+9 (max 1023), drop row i+4
        if (it < BH - 1) {
            {
                float nx[12], oxr[12];
                load12(xb + (size_t)(i + 9) * W, nx);
                load12(xb + (size_t)(i + 4) * W, oxr);
                #pragma unroll
                for (int k = 0; k < 12; ++k) cs_x[k] += nx[k] - oxr[k];
            }
            {
                float ny[12], oyr[12];
                load12(yb + (size_t)(i + 9) * W, ny);
                load12(yb + (size_t)(i + 4) * W, oyr);
                #pragma unroll
                for (int k = 0; k < 12; ++k) cs_y[k] += ny[k] - oyr[k];
            }
        }
    }
}

extern "C" void kernel_launch(void* const* d_in, const int* in_sizes, int n_in,
                              void* d_out, int out_size, void* d_ws, size_t ws_size,
                              hipStream_t stream) {
    const float* x = (const float*)d_in[0];
    const float* y = (const float*)d_in[1];
    // mask (d_in[2]) unused by the reference's channels==1 path
    float* out = (float*)d_out;
    const long long Nper = (long long)out_size / 3;   // elements per output array
    yiq_gngc_wave<<<dim3(NWG), dim3(64), 0, stream>>>(x, y, out, Nper);
}